// Round 6
// baseline (125.474 us; speedup 1.0000x reference)
//
#include <hip/hip_runtime.h>
#include <stdint.h>

// ---------------- problem constants ----------------
#define B    8192
#define D    256
#define C    7
#define NTOT 8199          // B + C
#define NPAD 8448          // 33 * 256 (padded rows)
#define NT   33            // 256-row tiles
#define NBLK 561           // 33*34/2 triangular
#define BETAC 0.005f       // 0.5*(1-GAMMA)
#define L2GAMMA (-0.0144995696951151f)  // log2(0.99)

using f32x4  = __attribute__((ext_vector_type(4))) float;

// bf16 round-to-nearest-even from f32 (unused for G now, kept for reference)
__device__ __forceinline__ unsigned short f2bf(float x) {
    unsigned u = __float_as_uint(x);
    unsigned r = (u + 0x7fffu + ((u >> 16) & 1u)) >> 16;
    return (unsigned short)r;
}

__device__ __forceinline__ void async16(const void* src, void* dst) {
    __builtin_amdgcn_global_load_lds(
        (const __attribute__((address_space(1))) void*)src,
        (__attribute__((address_space(3))) void*)dst, 16, 0, 0);
}

// score formula: ((1+sim)*0.5 + 1e-8) * 12.5 = sim*6.25 + (6.25 + 1.25e-7)
__device__ __forceinline__ float score_of(float sim) {
    return fmaf(sim, 6.25f, 6.25f + 1.25e-7f);
}

#define WAITVM(N) asm volatile("s_waitcnt vmcnt(" #N ")" ::: "memory")
#define BARRIER() do { __builtin_amdgcn_s_barrier(); asm volatile("" ::: "memory"); } while(0)

// ---------------- kernel 1: zero accums, ranks -> weights, labs_ext, histogram ----------------
__global__ void kprep(const int* __restrict__ labels, float* __restrict__ wbuf,
                      int* __restrict__ labs_ext, int* __restrict__ hist,
                      float* __restrict__ S, float* __restrict__ lossacc,
                      unsigned* __restrict__ ticket) {
    __shared__ int cnt[256 * 8];
    __shared__ int tot[8];
    int t = threadIdx.x;
    int lane = t & 63, w = t >> 6;
    for (int i = t; i < C * 256; i += 256) S[i] = 0.f;
    if (t == 0) { lossacc[0] = 0.f; lossacc[1] = 0.f; *ticket = 0u; }
    int lab[32];
    #pragma unroll
    for (int q = 0; q < 8; ++q) {
        int4 v = *(const int4*)(labels + t * 32 + q * 4);
        lab[q * 4 + 0] = v.x; lab[q * 4 + 1] = v.y;
        lab[q * 4 + 2] = v.z; lab[q * 4 + 3] = v.w;
    }
    int myc[8] = {0, 0, 0, 0, 0, 0, 0, 0};
    #pragma unroll
    for (int k = 0; k < 32; ++k) {
        #pragma unroll
        for (int cc = 0; cc < 7; ++cc) myc[cc] += (lab[k] == cc) ? 1 : 0;
    }
    #pragma unroll
    for (int cc = 0; cc < 8; ++cc) cnt[t * 8 + cc] = myc[cc];
    __syncthreads();
    for (int c = w; c < C; c += 4) {
        int v[4], partial = 0;
        #pragma unroll
        for (int k = 0; k < 4; ++k) { v[k] = cnt[(lane * 4 + k) * 8 + c]; partial += v[k]; }
        int inc = partial;
        #pragma unroll
        for (int d = 1; d < 64; d <<= 1) {
            int y = __shfl_up(inc, d);
            if (lane >= d) inc += y;
        }
        int run = inc - partial;
        #pragma unroll
        for (int k = 0; k < 4; ++k) { int tmp = v[k]; cnt[(lane * 4 + k) * 8 + c] = run; run += tmp; }
        if (lane == 63) { tot[c] = inc; hist[c] = inc; }
    }
    __syncthreads();
    #pragma unroll 4
    for (int k = 0; k < 32; ++k) {
        int idx = t * 32 + k;
        int c = lab[k];
        int r = ++cnt[t * 8 + c];
        int kk = tot[c] - r;
        wbuf[idx] = exp2f((float)kk * L2GAMMA);
    }
    for (int i = t; i < NPAD; i += 256)
        labs_ext[i] = (i < B) ? labels[i] : ((i < NTOT) ? (i - B) : -1);
}

// ---------------- kernel 2: fused normalize -> fp8 G + weighted class sums S ----------------
__global__ void kaccnorm(const float* __restrict__ feats, const int* __restrict__ labels,
                         const float* __restrict__ wbuf, float* __restrict__ S,
                         unsigned* __restrict__ G32) {
    __shared__ float sacc[4][7][256];
    int tid = threadIdx.x, lane = tid & 63, wv = tid >> 6;
    float acc7[7][4] = {};
    int base = blockIdx.x * 32 + wv * 8;
    for (int k = 0; k < 8; ++k) {
        int row = base + k;
        const float4 v = *(const float4*)(feats + (size_t)row * 256 + lane * 4);
        float ss = v.x * v.x + v.y * v.y + v.z * v.z + v.w * v.w;
        #pragma unroll
        for (int off = 1; off < 64; off <<= 1) ss += __shfl_xor(ss, off);
        float rn = 1.f / sqrtf(ss);
        // pack 4 normalized comps to fp8 e4m3 (OCP) via HW cvt
        unsigned p = (unsigned)__builtin_amdgcn_cvt_pk_fp8_f32(v.x * rn, v.y * rn, 0, false);
        p = (unsigned)__builtin_amdgcn_cvt_pk_fp8_f32(v.z * rn, v.w * rn, (int)p, true);
        G32[(size_t)row * 64 + lane] = p;
        int c = labels[row];               // wave-uniform
        float wgt = wbuf[row];
        float w0 = v.x * wgt, w1 = v.y * wgt, w2 = v.z * wgt, w3 = v.w * wgt;
        #pragma unroll
        for (int cc = 0; cc < 7; ++cc)
            if (c == cc) { acc7[cc][0] += w0; acc7[cc][1] += w1; acc7[cc][2] += w2; acc7[cc][3] += w3; }
    }
    #pragma unroll
    for (int cc = 0; cc < 7; ++cc) {
        #pragma unroll
        for (int jj = 0; jj < 4; ++jj)
            sacc[wv][cc][lane * 4 + jj] = acc7[cc][jj];
    }
    __syncthreads();
    #pragma unroll
    for (int cc = 0; cc < 7; ++cc) {
        float s = sacc[0][cc][tid] + sacc[1][cc][tid] + sacc[2][cc][tid] + sacc[3][cc][tid];
        atomicAdd(&S[cc * 256 + tid], s);
    }
    // zero the pad G rows (8199..8447), one row per block (64 uints per row)
    if (blockIdx.x < NPAD - NTOT && tid < 64)
        G32[(size_t)(NTOT + blockIdx.x) * 64 + tid] = 0u;
}

// ---------------- kernel 3: target build + Householder QR + fp8 proto G rows ----------------
__global__ void kproto(const float* __restrict__ S, const int* __restrict__ hist,
                       const float* __restrict__ protos, const float* __restrict__ moms,
                       unsigned char* __restrict__ G8) {
    __shared__ float A[256 * 8];
    __shared__ float V[256 * 8];
    __shared__ float vvs[8];
    __shared__ float bcast[8];
    int t = threadIdx.x;
    int lane = t & 63, w = t >> 6;
    #pragma unroll
    for (int c = 0; c < C; ++c) {
        float p = protos[c * 256 + t];
        float m0 = moms[c * 256 + t];
        float gn = exp2f((float)hist[c] * L2GAMMA);     // gamma^{n_c}
        float mf = gn * m0 + BETAC * S[c * 256 + t] - 0.5f * (1.f - gn) * p;
        A[t * 8 + c] = p + mf;
        V[t * 8 + c] = 0.f;
    }
    __syncthreads();
    for (int j = 0; j < C; ++j) {
        if (w == 0) {
            float s = 0.f;
            for (int i = lane; i < 256; i += 64) {
                float a = (i >= j) ? A[i * 8 + j] : 0.f;
                s += a * a;
            }
            #pragma unroll
            for (int off = 32; off; off >>= 1) s += __shfl_xor(s, off);
            if (lane == 0) {
                float norm = sqrtf(s);
                float alpha = A[j * 8 + j];
                float beta = (alpha >= 0.f) ? -norm : norm;
                float vv = 2.f * beta * (beta - alpha);
                bcast[0] = alpha; bcast[1] = beta;
                bcast[2] = (vv > 0.f) ? 1.f : 0.f;
                vvs[j] = (vv > 0.f) ? vv : 1.f;
            }
        }
        __syncthreads();
        float alpha = bcast[0], valid = bcast[2];
        float beta = bcast[1];
        float vi = 0.f;
        if (valid != 0.f) {
            if (t == j) vi = alpha - beta;
            else if (t > j) vi = A[t * 8 + j];
        }
        V[t * 8 + j] = vi;
        __syncthreads();
        float vvj = vvs[j];
        for (int k = j + 1 + w; k < C; k += 4) {
            float cp = 0.f;
            for (int i = lane; i < 256; i += 64) cp += V[i * 8 + j] * A[i * 8 + k];
            #pragma unroll
            for (int off = 32; off; off >>= 1) cp += __shfl_xor(cp, off);
            float scale = 2.f * cp / vvj;
            for (int i = lane; i < 256; i += 64) A[i * 8 + k] -= scale * V[i * 8 + j];
        }
        __syncthreads();
    }
    #pragma unroll
    for (int c = 0; c < C; ++c) A[t * 8 + c] = (t == c) ? 1.f : 0.f;
    __syncthreads();
    for (int j = C - 1; j >= 0; --j) {
        float vvj = vvs[j];
        for (int k = w; k < C; k += 4) {
            float cp = 0.f;
            for (int i = lane; i < 256; i += 64) cp += V[i * 8 + j] * A[i * 8 + k];
            #pragma unroll
            for (int off = 32; off; off >>= 1) cp += __shfl_xor(cp, off);
            float scale = 2.f * cp / vvj;
            for (int i = lane; i < 256; i += 64) A[i * 8 + k] -= scale * V[i * 8 + j];
        }
        __syncthreads();
    }
    for (int c = w; c < C; c += 4) {
        float s = 0.f;
        for (int i = lane; i < 256; i += 64) { float a = A[i * 8 + c]; s += a * a; }
        #pragma unroll
        for (int off = 32; off; off >>= 1) s += __shfl_xor(s, off);
        if (lane == 0) bcast[c] = 1.f / sqrtf(s);
    }
    __syncthreads();
    #pragma unroll
    for (int c = 0; c < C; ++c) {
        int pk = __builtin_amdgcn_cvt_pk_fp8_f32(A[t * 8 + c] * bcast[c], 0.f, 0, false);
        G8[(size_t)(B + c) * 256 + t] = (unsigned char)(pk & 0xff);
    }
}

// ---------------- kernel 4: 256x256 symmetric fused G G^T (fp8 MFMA) ----------------
__global__ __launch_bounds__(512, 2) void kmain(const unsigned char* __restrict__ G,
                                                const int* __restrict__ labs,
                                                float* __restrict__ pP,
                                                float* __restrict__ pN) {
    __shared__ unsigned char A2[2][256][64];      // double-buffered fp8 K-tiles (16 KB each)
    __shared__ unsigned char B2[2][256][64];
    __shared__ float rowP[4][256], rowN[4][256];  // cross-wc combine
    __shared__ float colP[2][256], colN[2][256];  // cross-wr combine

    // bijective XCD swizzle (561 = 8*70 + 1)
    int b0 = blockIdx.x;
    int xcd = b0 & 7, pos = b0 >> 3;
    int b = (xcd == 0) ? pos : (71 + (xcd - 1) * 70 + pos);

    // triangular decode: pairs (it <= jt)
    int jt = (int)((sqrtf(8.f * (float)b + 1.f) - 1.f) * 0.5f);
    while ((jt * (jt + 1)) / 2 > b) --jt;
    while (((jt + 1) * (jt + 2)) / 2 <= b) ++jt;
    int it = b - (jt * (jt + 1)) / 2;

    int rowA = it * 256, rowB = jt * 256;
    int tid = threadIdx.x, lane = tid & 63, w8 = tid >> 6;
    int wr = w8 >> 2, wc = w8 & 3;                // 2x4 wave grid

    const char* gb = (const char*)G;

    // stage one K-tile (BK=64 fp8 bytes) of A and B (256 rows each) into buffer BUF.
    // LDS dest linear; source col pre-permuted by the 16B-granular involution
    // sc = colb ^ ((row&3)<<4)  (rule #21: same permutation applied on read).
#define STAGE(BUF, KS)                                                         \
    do {                                                                       \
        _Pragma("unroll")                                                      \
        for (int q = 0; q < 2; ++q) {                                          \
            int o = q * 8192 + w8 * 1024 + lane * 16;                          \
            int row = o >> 6, colb = o & 63;                                   \
            int sc = colb ^ ((row & 3) << 4);                                  \
            const char* sA = gb + (size_t)(rowA + row) * 256 + (KS) * 64 + sc; \
            const char* sB = gb + (size_t)(rowB + row) * 256 + (KS) * 64 + sc; \
            async16(sA, (char*)A2 + (BUF) * 16384 + o);                        \
            async16(sB, (char*)B2 + (BUF) * 16384 + o);                        \
        }                                                                      \
    } while (0)

    STAGE(0, 0);
    STAGE(1, 1);

    f32x4 acc[8][4];
    #pragma unroll
    for (int m = 0; m < 8; ++m)
        #pragma unroll
        for (int n = 0; n < 4; ++n) acc[m][n] = 0.f;

#define KSTEP(BUF)                                                             \
    do {                                                                       \
        _Pragma("unroll")                                                      \
        for (int kk = 0; kk < 2; ++kk) {                                       \
            long af[8], bfr[4];                                                \
            _Pragma("unroll")                                                  \
            for (int m = 0; m < 8; ++m) {                                      \
                int r0 = wr * 128 + m * 16 + (lane & 15);                      \
                int cb = (kk * 32 + (lane >> 4) * 8) ^ ((r0 & 3) << 4);        \
                af[m] = *(const long*)((const char*)A2 + (BUF) * 16384 + r0 * 64 + cb); \
            }                                                                  \
            _Pragma("unroll")                                                  \
            for (int n = 0; n < 4; ++n) {                                      \
                int r0 = wc * 64 + n * 16 + (lane & 15);                       \
                int cb = (kk * 32 + (lane >> 4) * 8) ^ ((r0 & 3) << 4);        \
                bfr[n] = *(const long*)((const char*)B2 + (BUF) * 16384 + r0 * 64 + cb); \
            }                                                                  \
            __builtin_amdgcn_s_setprio(1);                                     \
            _Pragma("unroll")                                                  \
            for (int m = 0; m < 8; ++m)                                        \
                _Pragma("unroll")                                              \
                for (int n = 0; n < 4; ++n)                                    \
                    acc[m][n] = __builtin_amdgcn_mfma_f32_16x16x32_fp8_fp8(af[m], bfr[n], acc[m][n], 0, 0, 0); \
            __builtin_amdgcn_s_setprio(0);                                     \
        }                                                                      \
    } while (0)

    WAITVM(4); BARRIER();
    KSTEP(0);
    BARRIER(); STAGE(0, 2); WAITVM(4); BARRIER();
    KSTEP(1);
    BARRIER(); STAGE(1, 3); WAITVM(4); BARRIER();
    KSTEP(0);
    WAITVM(0); BARRIER();
    KSTEP(1);
#undef KSTEP
#undef STAGE

    // ---- fused epilogue: C/D layout col=lane&15, row=(lane>>4)*4+reg
    // labels read DIRECTLY from global (L2-hot) — no LDS staging.
    int g4 = lane >> 4, q15 = lane & 15;
    int ljv[4];
    #pragma unroll
    for (int n = 0; n < 4; ++n) ljv[n] = labs[rowB + wc * 64 + n * 16 + q15];
    float cs[4] = {0.f, 0.f, 0.f, 0.f}, cn[4] = {0.f, 0.f, 0.f, 0.f};
    bool fastpath = (it != jt) && (jt != NT - 1);

#define EPI(VALIDEXPR)                                                         \
    _Pragma("unroll")                                                          \
    for (int m = 0; m < 8; ++m) {                                              \
        int4 lrow = *(const int4*)(labs + rowA + wr * 128 + m * 16 + g4 * 4);  \
        _Pragma("unroll")                                                      \
        for (int r = 0; r < 4; ++r) {                                          \
            int il = wr * 128 + m * 16 + g4 * 4 + r;                           \
            int i = rowA + il; (void)i;                                        \
            int li = ((const int*)&lrow)[r];                                   \
            float ps = 0.f, ns = 0.f;                                          \
            _Pragma("unroll")                                                  \
            for (int n = 0; n < 4; ++n) {                                      \
                int j = rowB + wc * 64 + n * 16 + q15; (void)j;                \
                float sim = acc[m][n][r];                                      \
                float s = score_of(sim);                                       \
                float e = __expf(s);                                           \
                if (VALIDEXPR) {                                               \
                    if (li == ljv[n]) { ps += s; cs[n] += s; }                 \
                    else              { ns += e; cn[n] += e; }                 \
                }                                                              \
            }                                                                  \
            _Pragma("unroll")                                                  \
            for (int off = 1; off < 16; off <<= 1) {                           \
                ps += __shfl_xor(ps, off);                                     \
                ns += __shfl_xor(ns, off);                                     \
            }                                                                  \
            if (q15 == 0) { rowP[wc][il] = ps; rowN[wc][il] = ns; }            \
        }                                                                      \
    }

    if (fastpath) { EPI(true); }
    else          { EPI(i < NTOT && j < NTOT && i != j); }
#undef EPI

    // col-side: reduce over g4 groups (same q15-column, different rows)
    #pragma unroll
    for (int n = 0; n < 4; ++n) {
        float a = cs[n], bb = cn[n];
        a += __shfl_xor(a, 16); a += __shfl_xor(a, 32);
        bb += __shfl_xor(bb, 16); bb += __shfl_xor(bb, 32);
        if (g4 == 0) {
            colP[wr][wc * 64 + n * 16 + q15] = a;
            colN[wr][wc * 64 + n * 16 + q15] = bb;
        }
    }

    __syncthreads();
    if (tid < 256) {
        float sp = rowP[0][tid] + rowP[1][tid] + rowP[2][tid] + rowP[3][tid];
        float sn = rowN[0][tid] + rowN[1][tid] + rowN[2][tid] + rowN[3][tid];
        pP[(size_t)jt * NPAD + rowA + tid] = sp;
        pN[(size_t)jt * NPAD + rowA + tid] = sn;
    } else if (it != jt) {
        int tt = tid - 256;
        pP[(size_t)it * NPAD + rowB + tt] = colP[0][tt] + colP[1][tt];
        pN[(size_t)it * NPAD + rowB + tt] = colN[0][tt] + colN[1][tt];
    }
}

// ---------------- kernel 5: reduce partials -> loss, ticket finalize ----------------
__global__ void kreduce(const float* __restrict__ pP, const float* __restrict__ pN,
                        const int* __restrict__ hist, const int* __restrict__ labs,
                        float* __restrict__ lossacc, unsigned* __restrict__ ticket,
                        float* __restrict__ out) {
    int i = blockIdx.x * 256 + threadIdx.x;
    float lsum = 0.f, lcnt = 0.f;
    if (i < NTOT) {
        float sp = 0.f, sn = 0.f;
        #pragma unroll 3
        for (int c = 0; c < NT; ++c) {
            sp += pP[(size_t)c * NPAD + i];
            sn += pN[(size_t)c * NPAD + i];
        }
        // M = 0 shift: differs from reference's global-max shift by <=~1e-7
        float cnt = (float)hist[labs[i]];
        float pos = sp / (cnt + 1e-8f);
        float neg = logf(sn + 1e-8f);
        float loss = neg - pos;
        if (loss > 0.f) { lsum = loss; lcnt = 1.f; }
    }
    #pragma unroll
    for (int off = 1; off < 64; off <<= 1) {
        lsum += __shfl_xor(lsum, off);
        lcnt += __shfl_xor(lcnt, off);
    }
    __shared__ float s1[4], s2[4];
    int lane = threadIdx.x & 63, w = threadIdx.x >> 6;
    if (lane == 0) { s1[w] = lsum; s2[w] = lcnt; }
    __syncthreads();
    if (threadIdx.x == 0) {
        atomicAdd(&lossacc[0], s1[0] + s1[1] + s1[2] + s1[3]);
        atomicAdd(&lossacc[1], s2[0] + s2[1] + s2[2] + s2[3]);
        __threadfence();
        unsigned tk = atomicAdd(ticket, 1u);
        if (tk == 32) {   // last of 33 blocks: all adds visible
            float a = atomicAdd(&lossacc[0], 0.f);
            float c2 = atomicAdd(&lossacc[1], 0.f);
            out[0] = (c2 > 0.f) ? a / fmaxf(c2, 1.f) : 0.f;
        }
    }
}

// ---------------- launcher ----------------
extern "C" void kernel_launch(void* const* d_in, const int* in_sizes, int n_in,
                              void* d_out, int out_size, void* d_ws, size_t ws_size,
                              hipStream_t stream) {
    const float* feats  = (const float*)d_in[0];
    const int*   labels = (const int*)d_in[1];
    const float* protos = (const float*)d_in[2];
    const float* moms   = (const float*)d_in[3];
    float* out = (float*)d_out;

    char* ws = (char*)d_ws;
    float*    S_      = (float*)(ws + 0);        // 1792 f32 -> 7168
    int*      hist    = (int*)  (ws + 7168);     // 8 int    -> 7200
    float*    lossacc = (float*)(ws + 7200);     // 2 f32    -> 7208
    unsigned* ticket  = (unsigned*)(ws + 7208);  // 1 u32    -> 7212
    float*    wbuf    = (float*)(ws + 7296);     // 8192 f32 -> 40064
    int*      labs    = (int*)  (ws + 40064);    // 8448 int -> 73856
    unsigned char* G  = (unsigned char*)(ws + 73856);    // 8448*256 fp8 -> 2236544
    float*    pP      = (float*)(ws + 2236544);  // 33*8448 f32 -> 3351680
    float*    pN      = (float*)(ws + 3351680);  // 33*8448 f32 -> 4466816

    kprep<<<1, 256, 0, stream>>>(labels, wbuf, labs, hist, S_, lossacc, ticket);
    kaccnorm<<<256, 256, 0, stream>>>(feats, labels, wbuf, S_, (unsigned*)G);
    kproto<<<1, 256, 0, stream>>>(S_, hist, protos, moms, G);
    kmain<<<NBLK, 512, 0, stream>>>(G, labs, pP, pN);
    kreduce<<<33, 256, 0, stream>>>(pP, pN, hist, labs, lossacc, ticket, out);
}

// Round 7
// 110.049 us; speedup vs baseline: 1.1402x; 1.1402x over previous
//
#include <hip/hip_runtime.h>
#include <stdint.h>

// ---------------- problem constants ----------------
#define B    8192
#define D    256
#define C    7
#define NTOT 8199          // B + C
#define NPAD 8320          // 65 * 128 (padded rows)
#define NT   65            // 128-row tiles
#define NBLK 2145          // 65*66/2 triangular
#define BETAC 0.005f       // 0.5*(1-GAMMA)
#define L2GAMMA (-0.0144995696951151f)  // log2(0.99)

using f32x4  = __attribute__((ext_vector_type(4))) float;

__device__ __forceinline__ void async16(const void* src, void* dst) {
    __builtin_amdgcn_global_load_lds(
        (const __attribute__((address_space(1))) void*)src,
        (__attribute__((address_space(3))) void*)dst, 16, 0, 0);
}

// score formula: ((1+sim)*0.5 + 1e-8) * 12.5 = sim*6.25 + (6.25 + 1.25e-7)
__device__ __forceinline__ float score_of(float sim) {
    return fmaf(sim, 6.25f, 6.25f + 1.25e-7f);
}

#define WAITVM(N) asm volatile("s_waitcnt vmcnt(" #N ")" ::: "memory")
#define BARRIER() do { __builtin_amdgcn_s_barrier(); asm volatile("" ::: "memory"); } while(0)

// ---------------- kernel 1: zero accums, ranks -> weights, labs_ext, histogram ----------------
__global__ void kprep(const int* __restrict__ labels, float* __restrict__ wbuf,
                      int* __restrict__ labs_ext, int* __restrict__ hist,
                      float* __restrict__ S, float* __restrict__ lossacc,
                      unsigned* __restrict__ ticket) {
    __shared__ int cnt[256 * 8];
    __shared__ int tot[8];
    int t = threadIdx.x;
    int lane = t & 63, w = t >> 6;
    for (int i = t; i < C * 256; i += 256) S[i] = 0.f;
    if (t == 0) { lossacc[0] = 0.f; lossacc[1] = 0.f; *ticket = 0u; }
    int lab[32];
    #pragma unroll
    for (int q = 0; q < 8; ++q) {
        int4 v = *(const int4*)(labels + t * 32 + q * 4);
        lab[q * 4 + 0] = v.x; lab[q * 4 + 1] = v.y;
        lab[q * 4 + 2] = v.z; lab[q * 4 + 3] = v.w;
    }
    int myc[8] = {0, 0, 0, 0, 0, 0, 0, 0};
    #pragma unroll
    for (int k = 0; k < 32; ++k) {
        #pragma unroll
        for (int cc = 0; cc < 7; ++cc) myc[cc] += (lab[k] == cc) ? 1 : 0;
    }
    #pragma unroll
    for (int cc = 0; cc < 8; ++cc) cnt[t * 8 + cc] = myc[cc];
    __syncthreads();
    for (int c = w; c < C; c += 4) {
        int v[4], partial = 0;
        #pragma unroll
        for (int k = 0; k < 4; ++k) { v[k] = cnt[(lane * 4 + k) * 8 + c]; partial += v[k]; }
        int inc = partial;
        #pragma unroll
        for (int d = 1; d < 64; d <<= 1) {
            int y = __shfl_up(inc, d);
            if (lane >= d) inc += y;
        }
        int run = inc - partial;
        #pragma unroll
        for (int k = 0; k < 4; ++k) { int tmp = v[k]; cnt[(lane * 4 + k) * 8 + c] = run; run += tmp; }
        if (lane == 63) { tot[c] = inc; hist[c] = inc; }
    }
    __syncthreads();
    #pragma unroll 4
    for (int k = 0; k < 32; ++k) {
        int idx = t * 32 + k;
        int c = lab[k];
        int r = ++cnt[t * 8 + c];
        int kk = tot[c] - r;
        wbuf[idx] = exp2f((float)kk * L2GAMMA);
    }
    for (int i = t; i < NPAD; i += 256)
        labs_ext[i] = (i < B) ? labels[i] : ((i < NTOT) ? (i - B) : -1);
}

// ---------------- kernel 2: fused normalize -> fp8 G + weighted class sums S ----------------
__global__ void kaccnorm(const float* __restrict__ feats, const int* __restrict__ labels,
                         const float* __restrict__ wbuf, float* __restrict__ S,
                         unsigned* __restrict__ G32) {
    __shared__ float sacc[4][7][256];
    int tid = threadIdx.x, lane = tid & 63, wv = tid >> 6;
    float acc7[7][4] = {};
    int base = blockIdx.x * 32 + wv * 8;
    for (int k = 0; k < 8; ++k) {
        int row = base + k;
        const float4 v = *(const float4*)(feats + (size_t)row * 256 + lane * 4);
        float ss = v.x * v.x + v.y * v.y + v.z * v.z + v.w * v.w;
        #pragma unroll
        for (int off = 1; off < 64; off <<= 1) ss += __shfl_xor(ss, off);
        float rn = 1.f / sqrtf(ss);
        unsigned p = (unsigned)__builtin_amdgcn_cvt_pk_fp8_f32(v.x * rn, v.y * rn, 0, false);
        p = (unsigned)__builtin_amdgcn_cvt_pk_fp8_f32(v.z * rn, v.w * rn, (int)p, true);
        G32[(size_t)row * 64 + lane] = p;
        int c = labels[row];               // wave-uniform
        float wgt = wbuf[row];
        float w0 = v.x * wgt, w1 = v.y * wgt, w2 = v.z * wgt, w3 = v.w * wgt;
        #pragma unroll
        for (int cc = 0; cc < 7; ++cc)
            if (c == cc) { acc7[cc][0] += w0; acc7[cc][1] += w1; acc7[cc][2] += w2; acc7[cc][3] += w3; }
    }
    #pragma unroll
    for (int cc = 0; cc < 7; ++cc) {
        #pragma unroll
        for (int jj = 0; jj < 4; ++jj)
            sacc[wv][cc][lane * 4 + jj] = acc7[cc][jj];
    }
    __syncthreads();
    #pragma unroll
    for (int cc = 0; cc < 7; ++cc) {
        float s = sacc[0][cc][tid] + sacc[1][cc][tid] + sacc[2][cc][tid] + sacc[3][cc][tid];
        atomicAdd(&S[cc * 256 + tid], s);
    }
    // zero the pad G rows (8199..8319), one row per block (64 uints per row)
    if (blockIdx.x < NPAD - NTOT && tid < 64)
        G32[(size_t)(NTOT + blockIdx.x) * 64 + tid] = 0u;
}

// ---------------- kernel 3: target build + Householder QR + fp8 proto G rows ----------------
__global__ void kproto(const float* __restrict__ S, const int* __restrict__ hist,
                       const float* __restrict__ protos, const float* __restrict__ moms,
                       unsigned char* __restrict__ G8) {
    __shared__ float A[256 * 8];
    __shared__ float V[256 * 8];
    __shared__ float vvs[8];
    __shared__ float bcast[8];
    int t = threadIdx.x;
    int lane = t & 63, w = t >> 6;
    #pragma unroll
    for (int c = 0; c < C; ++c) {
        float p = protos[c * 256 + t];
        float m0 = moms[c * 256 + t];
        float gn = exp2f((float)hist[c] * L2GAMMA);     // gamma^{n_c}
        float mf = gn * m0 + BETAC * S[c * 256 + t] - 0.5f * (1.f - gn) * p;
        A[t * 8 + c] = p + mf;
        V[t * 8 + c] = 0.f;
    }
    __syncthreads();
    for (int j = 0; j < C; ++j) {
        if (w == 0) {
            float s = 0.f;
            for (int i = lane; i < 256; i += 64) {
                float a = (i >= j) ? A[i * 8 + j] : 0.f;
                s += a * a;
            }
            #pragma unroll
            for (int off = 32; off; off >>= 1) s += __shfl_xor(s, off);
            if (lane == 0) {
                float norm = sqrtf(s);
                float alpha = A[j * 8 + j];
                float beta = (alpha >= 0.f) ? -norm : norm;
                float vv = 2.f * beta * (beta - alpha);
                bcast[0] = alpha; bcast[1] = beta;
                bcast[2] = (vv > 0.f) ? 1.f : 0.f;
                vvs[j] = (vv > 0.f) ? vv : 1.f;
            }
        }
        __syncthreads();
        float alpha = bcast[0], valid = bcast[2];
        float beta = bcast[1];
        float vi = 0.f;
        if (valid != 0.f) {
            if (t == j) vi = alpha - beta;
            else if (t > j) vi = A[t * 8 + j];
        }
        V[t * 8 + j] = vi;
        __syncthreads();
        float vvj = vvs[j];
        for (int k = j + 1 + w; k < C; k += 4) {
            float cp = 0.f;
            for (int i = lane; i < 256; i += 64) cp += V[i * 8 + j] * A[i * 8 + k];
            #pragma unroll
            for (int off = 32; off; off >>= 1) cp += __shfl_xor(cp, off);
            float scale = 2.f * cp / vvj;
            for (int i = lane; i < 256; i += 64) A[i * 8 + k] -= scale * V[i * 8 + j];
        }
        __syncthreads();
    }
    #pragma unroll
    for (int c = 0; c < C; ++c) A[t * 8 + c] = (t == c) ? 1.f : 0.f;
    __syncthreads();
    for (int j = C - 1; j >= 0; --j) {
        float vvj = vvs[j];
        for (int k = w; k < C; k += 4) {
            float cp = 0.f;
            for (int i = lane; i < 256; i += 64) cp += V[i * 8 + j] * A[i * 8 + k];
            #pragma unroll
            for (int off = 32; off; off >>= 1) cp += __shfl_xor(cp, off);
            float scale = 2.f * cp / vvj;
            for (int i = lane; i < 256; i += 64) A[i * 8 + k] -= scale * V[i * 8 + j];
        }
        __syncthreads();
    }
    for (int c = w; c < C; c += 4) {
        float s = 0.f;
        for (int i = lane; i < 256; i += 64) { float a = A[i * 8 + c]; s += a * a; }
        #pragma unroll
        for (int off = 32; off; off >>= 1) s += __shfl_xor(s, off);
        if (lane == 0) bcast[c] = 1.f / sqrtf(s);
    }
    __syncthreads();
    #pragma unroll
    for (int c = 0; c < C; ++c) {
        int pk = __builtin_amdgcn_cvt_pk_fp8_f32(A[t * 8 + c] * bcast[c], 0.f, 0, false);
        G8[(size_t)(B + c) * 256 + t] = (unsigned char)(pk & 0xff);
    }
}

// ---------------- kernel 4: 128x128 symmetric fused G G^T, single-stage full-K ----------------
__global__ __launch_bounds__(256, 2) void kmain(const unsigned char* __restrict__ G,
                                                const int* __restrict__ labs,
                                                float* __restrict__ pP,
                                                float* __restrict__ pN) {
    __shared__ unsigned char Asm_[128 * 256];   // full-K fp8 A tile (32 KB)
    __shared__ unsigned char Bsm_[128 * 256];   // full-K fp8 B tile (32 KB)
    // epilogue overlays into Asm_ (after a barrier): 4 x [2][128] floats = 4 KB
    float* rowP = (float*)Asm_;
    float* rowN = rowP + 256;
    float* colP = rowN + 256;
    float* colN = colP + 256;

    // bijective XCD swizzle: NBLK = 2145 = 8*268 + 1 (residue 0 gets 269)
    int b0 = blockIdx.x;
    int xcd = b0 & 7, pos = b0 >> 3;
    int b = (xcd == 0) ? pos : (269 + (xcd - 1) * 268 + pos);

    // triangular decode: pairs (it <= jt)
    int jt = (int)((sqrtf(8.f * (float)b + 1.f) - 1.f) * 0.5f);
    while ((jt * (jt + 1)) / 2 > b) --jt;
    while (((jt + 1) * (jt + 2)) / 2 <= b) ++jt;
    int it = b - (jt * (jt + 1)) / 2;

    int rowA = it * 128, rowB = jt * 128;
    int tid = threadIdx.x, lane = tid & 63, w4 = tid >> 6;
    int wr = w4 >> 1, wc = w4 & 1;                // 2x2 wave grid
    int g4 = lane >> 4, q15 = lane & 15;

    const char* gb = (const char*)G;

    // ---- single-shot staging: all 16 loads in flight (max MLP), one wait.
    // LDS linear; source col pre-permuted by the 16B-granular involution
    // sc = colb ^ ((row&15)<<4); same XOR applied on the ds_read side.
    #pragma unroll
    for (int q = 0; q < 8; ++q) {
        int o = q * 4096 + tid * 16;
        int row = o >> 8, colb = o & 255;
        int sc = colb ^ ((row & 15) << 4);
        async16(gb + (size_t)(rowA + row) * 256 + sc, (char*)Asm_ + o);
    }
    #pragma unroll
    for (int q = 0; q < 8; ++q) {
        int o = q * 4096 + tid * 16;
        int row = o >> 8, colb = o & 255;
        int sc = colb ^ ((row & 15) << 4);
        async16(gb + (size_t)(rowB + row) * 256 + sc, (char*)Bsm_ + o);
    }

    // label prefetch into registers — overlaps the stage latency
    int ljv[4];
    #pragma unroll
    for (int n = 0; n < 4; ++n) ljv[n] = labs[rowB + wc * 64 + n * 16 + q15];
    int4 lrow[4];
    #pragma unroll
    for (int m = 0; m < 4; ++m)
        lrow[m] = *(const int4*)(labs + rowA + wr * 64 + m * 16 + g4 * 4);

    f32x4 acc[4][4];
    #pragma unroll
    for (int m = 0; m < 4; ++m)
        #pragma unroll
        for (int n = 0; n < 4; ++n) acc[m][n] = 0.f;

    WAITVM(0);
    BARRIER();

    // ---- mega K-step: 128 MFMA per wave, no barriers, compiler-scheduled lgkmcnt
    #pragma unroll
    for (int kk = 0; kk < 8; ++kk) {
        long af[4], bfr[4];
        int cb = (kk * 32 + g4 * 8) ^ (q15 << 4);   // r0&15 == lane&15 always
        #pragma unroll
        for (int m = 0; m < 4; ++m) {
            int r0 = wr * 64 + m * 16 + q15;
            af[m] = *(const long*)((const char*)Asm_ + r0 * 256 + cb);
        }
        #pragma unroll
        for (int n = 0; n < 4; ++n) {
            int r0 = wc * 64 + n * 16 + q15;
            bfr[n] = *(const long*)((const char*)Bsm_ + r0 * 256 + cb);
        }
        __builtin_amdgcn_s_setprio(1);
        #pragma unroll
        for (int m = 0; m < 4; ++m)
            #pragma unroll
            for (int n = 0; n < 4; ++n)
                acc[m][n] = __builtin_amdgcn_mfma_f32_16x16x32_fp8_fp8(af[m], bfr[n], acc[m][n], 0, 0, 0);
        __builtin_amdgcn_s_setprio(0);
    }

    __syncthreads();   // all LDS reads done before epilogue overlay writes

    // ---- fused epilogue: C/D layout col=lane&15, row=(lane>>4)*4+reg
    float cs[4] = {0.f, 0.f, 0.f, 0.f}, cn[4] = {0.f, 0.f, 0.f, 0.f};
    bool fastpath = (it != jt) && (jt != NT - 1);

#define EPI(VALIDEXPR)                                                         \
    _Pragma("unroll")                                                          \
    for (int m = 0; m < 4; ++m) {                                              \
        _Pragma("unroll")                                                      \
        for (int r = 0; r < 4; ++r) {                                          \
            int il = wr * 64 + m * 16 + g4 * 4 + r;                            \
            int i = rowA + il; (void)i;                                        \
            int li = ((const int*)&lrow[m])[r];                                \
            float ps = 0.f, ns = 0.f;                                          \
            _Pragma("unroll")                                                  \
            for (int n = 0; n < 4; ++n) {                                      \
                int j = rowB + wc * 64 + n * 16 + q15; (void)j;                \
                float sim = acc[m][n][r];                                      \
                float s = score_of(sim);                                       \
                float e = __expf(s);                                           \
                if (VALIDEXPR) {                                               \
                    if (li == ljv[n]) { ps += s; cs[n] += s; }                 \
                    else              { ns += e; cn[n] += e; }                 \
                }                                                              \
            }                                                                  \
            _Pragma("unroll")                                                  \
            for (int off = 1; off < 16; off <<= 1) {                           \
                ps += __shfl_xor(ps, off);                                     \
                ns += __shfl_xor(ns, off);                                     \
            }                                                                  \
            if (q15 == 0) { rowP[wc * 128 + il] = ps; rowN[wc * 128 + il] = ns; } \
        }                                                                      \
    }

    if (fastpath) { EPI(true); }
    else          { EPI(i < NTOT && j < NTOT && i != j); }
#undef EPI

    // col-side: reduce over g4 groups (same q15-column, different rows)
    #pragma unroll
    for (int n = 0; n < 4; ++n) {
        float a = cs[n], bb = cn[n];
        a += __shfl_xor(a, 16); a += __shfl_xor(a, 32);
        bb += __shfl_xor(bb, 16); bb += __shfl_xor(bb, 32);
        if (g4 == 0) {
            colP[wr * 128 + wc * 64 + n * 16 + q15] = a;
            colN[wr * 128 + wc * 64 + n * 16 + q15] = bb;
        }
    }

    __syncthreads();
    if (tid < 128) {
        pP[(size_t)jt * NPAD + rowA + tid] = rowP[tid] + rowP[128 + tid];
        pN[(size_t)jt * NPAD + rowA + tid] = rowN[tid] + rowN[128 + tid];
    } else if (it != jt) {
        int tt = tid - 128;
        pP[(size_t)it * NPAD + rowB + tt] = colP[tt] + colP[128 + tt];
        pN[(size_t)it * NPAD + rowB + tt] = colN[tt] + colN[128 + tt];
    }
}

// ---------------- kernel 5: reduce partials -> loss, ticket finalize ----------------
__global__ void kreduce(const float* __restrict__ pP, const float* __restrict__ pN,
                        const int* __restrict__ hist, const int* __restrict__ labs,
                        float* __restrict__ lossacc, unsigned* __restrict__ ticket,
                        float* __restrict__ out) {
    int i = blockIdx.x * 256 + threadIdx.x;
    float lsum = 0.f, lcnt = 0.f;
    if (i < NTOT) {
        float sp = 0.f, sn = 0.f;
        #pragma unroll 5
        for (int c = 0; c < NT; ++c) {
            sp += pP[(size_t)c * NPAD + i];
            sn += pN[(size_t)c * NPAD + i];
        }
        // M = 0 shift: differs from reference's global-max shift by <=~1e-7
        float cnt = (float)hist[labs[i]];
        float pos = sp / (cnt + 1e-8f);
        float neg = logf(sn + 1e-8f);
        float loss = neg - pos;
        if (loss > 0.f) { lsum = loss; lcnt = 1.f; }
    }
    #pragma unroll
    for (int off = 1; off < 64; off <<= 1) {
        lsum += __shfl_xor(lsum, off);
        lcnt += __shfl_xor(lcnt, off);
    }
    __shared__ float s1[4], s2[4];
    int lane = threadIdx.x & 63, w = threadIdx.x >> 6;
    if (lane == 0) { s1[w] = lsum; s2[w] = lcnt; }
    __syncthreads();
    if (threadIdx.x == 0) {
        atomicAdd(&lossacc[0], s1[0] + s1[1] + s1[2] + s1[3]);
        atomicAdd(&lossacc[1], s2[0] + s2[1] + s2[2] + s2[3]);
        __threadfence();
        unsigned tk = atomicAdd(ticket, 1u);
        if (tk == 32) {   // last of 33 blocks: all adds visible
            float a = atomicAdd(&lossacc[0], 0.f);
            float c2 = atomicAdd(&lossacc[1], 0.f);
            out[0] = (c2 > 0.f) ? a / fmaxf(c2, 1.f) : 0.f;
        }
    }
}

// ---------------- launcher ----------------
extern "C" void kernel_launch(void* const* d_in, const int* in_sizes, int n_in,
                              void* d_out, int out_size, void* d_ws, size_t ws_size,
                              hipStream_t stream) {
    const float* feats  = (const float*)d_in[0];
    const int*   labels = (const int*)d_in[1];
    const float* protos = (const float*)d_in[2];
    const float* moms   = (const float*)d_in[3];
    float* out = (float*)d_out;

    char* ws = (char*)d_ws;
    float*    S_      = (float*)(ws + 0);        // 1792 f32 -> 7168
    int*      hist    = (int*)  (ws + 7168);     // 8 int    -> 7200
    float*    lossacc = (float*)(ws + 7200);     // 2 f32    -> 7208
    unsigned* ticket  = (unsigned*)(ws + 7208);  // 1 u32    -> 7212
    float*    wbuf    = (float*)(ws + 7296);     // 8192 f32 -> 40064
    int*      labs    = (int*)  (ws + 40064);    // 8320 int -> 73344
    unsigned char* G  = (unsigned char*)(ws + 73344);    // 8320*256 fp8 -> 2203264
    float*    pP      = (float*)(ws + 2203264);  // 65*8320 f32 -> 4366464
    float*    pN      = (float*)(ws + 4366464);  // 65*8320 f32 -> 6529664

    kprep<<<1, 256, 0, stream>>>(labels, wbuf, labs, hist, S_, lossacc, ticket);
    kaccnorm<<<256, 256, 0, stream>>>(feats, labels, wbuf, S_, (unsigned*)G);
    kproto<<<1, 256, 0, stream>>>(S_, hist, protos, moms, G);
    kmain<<<NBLK, 256, 0, stream>>>(G, labs, pP, pN);
    kreduce<<<33, 256, 0, stream>>>(pP, pN, hist, labs, lossacc, ticket, out);
}

// Round 8
// 104.988 us; speedup vs baseline: 1.1951x; 1.0482x over previous
//
#include <hip/hip_runtime.h>
#include <stdint.h>

// ---------------- problem constants ----------------
#define B    8192
#define D    256
#define C    7
#define NTOT 8199          // B + C
#define NPAD 8320          // 65 * 128 (padded rows)
#define NT   65            // 128-row tiles
#define NBLK 2145          // 65*66/2 triangular
#define BETAC 0.005f       // 0.5*(1-GAMMA)
#define L2GAMMA (-0.0144995696951151f)  // log2(0.99)

using f32x4  = __attribute__((ext_vector_type(4))) float;

__device__ __forceinline__ void async16(const void* src, void* dst) {
    __builtin_amdgcn_global_load_lds(
        (const __attribute__((address_space(1))) void*)src,
        (__attribute__((address_space(3))) void*)dst, 16, 0, 0);
}

// score formula: ((1+sim)*0.5 + 1e-8) * 12.5 = sim*6.25 + (6.25 + 1.25e-7)
__device__ __forceinline__ float score_of(float sim) {
    return fmaf(sim, 6.25f, 6.25f + 1.25e-7f);
}

#define WAITVM(N) asm volatile("s_waitcnt vmcnt(" #N ")" ::: "memory")
#define BARRIER() do { __builtin_amdgcn_s_barrier(); asm volatile("" ::: "memory"); } while(0)

// ---------------- kernel 1: zero accums, ranks -> weights, labs_ext, histogram ----------------
__global__ void kprep(const int* __restrict__ labels, float* __restrict__ wbuf,
                      int* __restrict__ labs_ext, int* __restrict__ hist,
                      float* __restrict__ S, float* __restrict__ lossacc,
                      unsigned* __restrict__ ticket) {
    __shared__ int cnt[256 * 8];
    __shared__ int tot[8];
    int t = threadIdx.x;
    int lane = t & 63, w = t >> 6;
    for (int i = t; i < C * 256; i += 256) S[i] = 0.f;
    if (t == 0) { lossacc[0] = 0.f; lossacc[1] = 0.f; *ticket = 0u; }
    int lab[32];
    #pragma unroll
    for (int q = 0; q < 8; ++q) {
        int4 v = *(const int4*)(labels + t * 32 + q * 4);
        lab[q * 4 + 0] = v.x; lab[q * 4 + 1] = v.y;
        lab[q * 4 + 2] = v.z; lab[q * 4 + 3] = v.w;
    }
    int myc[8] = {0, 0, 0, 0, 0, 0, 0, 0};
    #pragma unroll
    for (int k = 0; k < 32; ++k) {
        #pragma unroll
        for (int cc = 0; cc < 7; ++cc) myc[cc] += (lab[k] == cc) ? 1 : 0;
    }
    #pragma unroll
    for (int cc = 0; cc < 8; ++cc) cnt[t * 8 + cc] = myc[cc];
    __syncthreads();
    for (int c = w; c < C; c += 4) {
        int v[4], partial = 0;
        #pragma unroll
        for (int k = 0; k < 4; ++k) { v[k] = cnt[(lane * 4 + k) * 8 + c]; partial += v[k]; }
        int inc = partial;
        #pragma unroll
        for (int d = 1; d < 64; d <<= 1) {
            int y = __shfl_up(inc, d);
            if (lane >= d) inc += y;
        }
        int run = inc - partial;
        #pragma unroll
        for (int k = 0; k < 4; ++k) { int tmp = v[k]; cnt[(lane * 4 + k) * 8 + c] = run; run += tmp; }
        if (lane == 63) { tot[c] = inc; hist[c] = inc; }
    }
    __syncthreads();
    #pragma unroll 4
    for (int k = 0; k < 32; ++k) {
        int idx = t * 32 + k;
        int c = lab[k];
        int r = ++cnt[t * 8 + c];
        int kk = tot[c] - r;
        wbuf[idx] = exp2f((float)kk * L2GAMMA);
    }
    for (int i = t; i < NPAD; i += 256)
        labs_ext[i] = (i < B) ? labels[i] : ((i < NTOT) ? (i - B) : -1);
}

// ---------------- kernel 2: fused normalize -> fp8 G + weighted class sums S ----------------
__global__ void kaccnorm(const float* __restrict__ feats, const int* __restrict__ labels,
                         const float* __restrict__ wbuf, float* __restrict__ S,
                         unsigned* __restrict__ G32) {
    __shared__ float sacc[4][7][256];
    int tid = threadIdx.x, lane = tid & 63, wv = tid >> 6;
    float acc7[7][4] = {};
    int base = blockIdx.x * 32 + wv * 8;
    for (int k = 0; k < 8; ++k) {
        int row = base + k;
        const float4 v = *(const float4*)(feats + (size_t)row * 256 + lane * 4);
        float ss = v.x * v.x + v.y * v.y + v.z * v.z + v.w * v.w;
        #pragma unroll
        for (int off = 1; off < 64; off <<= 1) ss += __shfl_xor(ss, off);
        float rn = 1.f / sqrtf(ss);
        unsigned p = (unsigned)__builtin_amdgcn_cvt_pk_fp8_f32(v.x * rn, v.y * rn, 0, false);
        p = (unsigned)__builtin_amdgcn_cvt_pk_fp8_f32(v.z * rn, v.w * rn, (int)p, true);
        G32[(size_t)row * 64 + lane] = p;
        int c = labels[row];               // wave-uniform
        float wgt = wbuf[row];
        float w0 = v.x * wgt, w1 = v.y * wgt, w2 = v.z * wgt, w3 = v.w * wgt;
        #pragma unroll
        for (int cc = 0; cc < 7; ++cc)
            if (c == cc) { acc7[cc][0] += w0; acc7[cc][1] += w1; acc7[cc][2] += w2; acc7[cc][3] += w3; }
    }
    #pragma unroll
    for (int cc = 0; cc < 7; ++cc) {
        #pragma unroll
        for (int jj = 0; jj < 4; ++jj)
            sacc[wv][cc][lane * 4 + jj] = acc7[cc][jj];
    }
    __syncthreads();
    #pragma unroll
    for (int cc = 0; cc < 7; ++cc) {
        float s = sacc[0][cc][tid] + sacc[1][cc][tid] + sacc[2][cc][tid] + sacc[3][cc][tid];
        atomicAdd(&S[cc * 256 + tid], s);
    }
    // zero the pad G rows (8199..8319), one row per block (64 uints per row)
    if (blockIdx.x < NPAD - NTOT && tid < 64)
        G32[(size_t)(NTOT + blockIdx.x) * 64 + tid] = 0u;
}

// ---------------- kernel 3: target build + Householder QR + fp8 proto G rows ----------------
__global__ void kproto(const float* __restrict__ S, const int* __restrict__ hist,
                       const float* __restrict__ protos, const float* __restrict__ moms,
                       unsigned char* __restrict__ G8) {
    __shared__ float A[256 * 8];
    __shared__ float V[256 * 8];
    __shared__ float vvs[8];
    __shared__ float bcast[8];
    int t = threadIdx.x;
    int lane = t & 63, w = t >> 6;
    #pragma unroll
    for (int c = 0; c < C; ++c) {
        float p = protos[c * 256 + t];
        float m0 = moms[c * 256 + t];
        float gn = exp2f((float)hist[c] * L2GAMMA);     // gamma^{n_c}
        float mf = gn * m0 + BETAC * S[c * 256 + t] - 0.5f * (1.f - gn) * p;
        A[t * 8 + c] = p + mf;
        V[t * 8 + c] = 0.f;
    }
    __syncthreads();
    for (int j = 0; j < C; ++j) {
        if (w == 0) {
            float s = 0.f;
            for (int i = lane; i < 256; i += 64) {
                float a = (i >= j) ? A[i * 8 + j] : 0.f;
                s += a * a;
            }
            #pragma unroll
            for (int off = 32; off; off >>= 1) s += __shfl_xor(s, off);
            if (lane == 0) {
                float norm = sqrtf(s);
                float alpha = A[j * 8 + j];
                float beta = (alpha >= 0.f) ? -norm : norm;
                float vv = 2.f * beta * (beta - alpha);
                bcast[0] = alpha; bcast[1] = beta;
                bcast[2] = (vv > 0.f) ? 1.f : 0.f;
                vvs[j] = (vv > 0.f) ? vv : 1.f;
            }
        }
        __syncthreads();
        float alpha = bcast[0], valid = bcast[2];
        float beta = bcast[1];
        float vi = 0.f;
        if (valid != 0.f) {
            if (t == j) vi = alpha - beta;
            else if (t > j) vi = A[t * 8 + j];
        }
        V[t * 8 + j] = vi;
        __syncthreads();
        float vvj = vvs[j];
        for (int k = j + 1 + w; k < C; k += 4) {
            float cp = 0.f;
            for (int i = lane; i < 256; i += 64) cp += V[i * 8 + j] * A[i * 8 + k];
            #pragma unroll
            for (int off = 32; off; off >>= 1) cp += __shfl_xor(cp, off);
            float scale = 2.f * cp / vvj;
            for (int i = lane; i < 256; i += 64) A[i * 8 + k] -= scale * V[i * 8 + j];
        }
        __syncthreads();
    }
    #pragma unroll
    for (int c = 0; c < C; ++c) A[t * 8 + c] = (t == c) ? 1.f : 0.f;
    __syncthreads();
    for (int j = C - 1; j >= 0; --j) {
        float vvj = vvs[j];
        for (int k = w; k < C; k += 4) {
            float cp = 0.f;
            for (int i = lane; i < 256; i += 64) cp += V[i * 8 + j] * A[i * 8 + k];
            #pragma unroll
            for (int off = 32; off; off >>= 1) cp += __shfl_xor(cp, off);
            float scale = 2.f * cp / vvj;
            for (int i = lane; i < 256; i += 64) A[i * 8 + k] -= scale * V[i * 8 + j];
        }
        __syncthreads();
    }
    for (int c = w; c < C; c += 4) {
        float s = 0.f;
        for (int i = lane; i < 256; i += 64) { float a = A[i * 8 + c]; s += a * a; }
        #pragma unroll
        for (int off = 32; off; off >>= 1) s += __shfl_xor(s, off);
        if (lane == 0) bcast[c] = 1.f / sqrtf(s);
    }
    __syncthreads();
    #pragma unroll
    for (int c = 0; c < C; ++c) {
        int pk = __builtin_amdgcn_cvt_pk_fp8_f32(A[t * 8 + c] * bcast[c], 0.f, 0, false);
        G8[(size_t)(B + c) * 256 + t] = (unsigned char)(pk & 0xff);
    }
}

// ---------------- kernel 4: 128x128 symmetric fused G G^T, 8 waves, full-K single stage ----------------
__global__ __launch_bounds__(512, 2) void kmain(const unsigned char* __restrict__ G,
                                                const int* __restrict__ labs,
                                                float* __restrict__ pP,
                                                float* __restrict__ pN) {
    __shared__ unsigned char Asm_[128 * 256];   // full-K fp8 A tile (32 KB)
    __shared__ unsigned char Bsm_[128 * 256];   // full-K fp8 B tile (32 KB)
    // epilogue overlays into Asm_ (after a barrier): 12 x [128] floats = 6 KB
    float* rowP = (float*)Asm_;                 // [2][128]
    float* rowN = rowP + 256;                   // [2][128]
    float* colP = rowN + 256;                   // [4][128]
    float* colN = colP + 512;                   // [4][128]

    // bijective XCD swizzle: NBLK = 2145 = 8*268 + 1 (residue 0 gets 269)
    int b0 = blockIdx.x;
    int xcd = b0 & 7, pos = b0 >> 3;
    int b = (xcd == 0) ? pos : (269 + (xcd - 1) * 268 + pos);

    // triangular decode: pairs (it <= jt)
    int jt = (int)((sqrtf(8.f * (float)b + 1.f) - 1.f) * 0.5f);
    while ((jt * (jt + 1)) / 2 > b) --jt;
    while (((jt + 1) * (jt + 2)) / 2 <= b) ++jt;
    int it = b - (jt * (jt + 1)) / 2;

    int rowA = it * 128, rowB = jt * 128;
    int tid = threadIdx.x, lane = tid & 63, w8 = tid >> 6;
    int wr = w8 >> 1, wc = w8 & 1;              // 4x2 wave grid: 32 rows x 64 cols per wave
    int g4 = lane >> 4, q15 = lane & 15;

    const char* gb = (const char*)G;

    // ---- single-shot staging: 8 loads/thread in flight, one wait.
    // LDS linear; source col pre-permuted by the 16B-granular involution
    // sc = colb ^ ((row&15)<<4); same XOR applied on the ds_read side.
    #pragma unroll
    for (int q = 0; q < 4; ++q) {
        int o = q * 8192 + tid * 16;
        int row = o >> 8, colb = o & 255;
        int sc = colb ^ ((row & 15) << 4);
        async16(gb + (size_t)(rowA + row) * 256 + sc, (char*)Asm_ + o);
    }
    #pragma unroll
    for (int q = 0; q < 4; ++q) {
        int o = q * 8192 + tid * 16;
        int row = o >> 8, colb = o & 255;
        int sc = colb ^ ((row & 15) << 4);
        async16(gb + (size_t)(rowB + row) * 256 + sc, (char*)Bsm_ + o);
    }

    // label prefetch into registers — overlaps the stage latency
    int ljv[4];
    #pragma unroll
    for (int n = 0; n < 4; ++n) ljv[n] = labs[rowB + wc * 64 + n * 16 + q15];
    int4 lrow[2];
    #pragma unroll
    for (int m = 0; m < 2; ++m)
        lrow[m] = *(const int4*)(labs + rowA + wr * 32 + m * 16 + g4 * 4);

    f32x4 acc[2][4];
    #pragma unroll
    for (int m = 0; m < 2; ++m)
        #pragma unroll
        for (int n = 0; n < 4; ++n) acc[m][n] = 0.f;

    WAITVM(0);
    BARRIER();

    // ---- mega K-step: 64 MFMA per wave, no barriers
    #pragma unroll
    for (int kk = 0; kk < 8; ++kk) {
        long af[2], bfr[4];
        int cb = (kk * 32 + g4 * 8) ^ (q15 << 4);
        #pragma unroll
        for (int m = 0; m < 2; ++m) {
            int r0 = wr * 32 + m * 16 + q15;
            af[m] = *(const long*)((const char*)Asm_ + r0 * 256 + cb);
        }
        #pragma unroll
        for (int n = 0; n < 4; ++n) {
            int r0 = wc * 64 + n * 16 + q15;
            bfr[n] = *(const long*)((const char*)Bsm_ + r0 * 256 + cb);
        }
        __builtin_amdgcn_s_setprio(1);
        #pragma unroll
        for (int m = 0; m < 2; ++m)
            #pragma unroll
            for (int n = 0; n < 4; ++n)
                acc[m][n] = __builtin_amdgcn_mfma_f32_16x16x32_fp8_fp8(af[m], bfr[n], acc[m][n], 0, 0, 0);
        __builtin_amdgcn_s_setprio(0);
    }

    __syncthreads();   // all LDS reads done before epilogue overlay writes

    // ---- fused epilogue: C/D layout col=lane&15, row=(lane>>4)*4+reg
    float cs[4] = {0.f, 0.f, 0.f, 0.f}, cn[4] = {0.f, 0.f, 0.f, 0.f};
    bool fastpath = (it != jt) && (jt != NT - 1);

#define EPI(VALIDEXPR)                                                         \
    _Pragma("unroll")                                                          \
    for (int m = 0; m < 2; ++m) {                                              \
        _Pragma("unroll")                                                      \
        for (int r = 0; r < 4; ++r) {                                          \
            int il = wr * 32 + m * 16 + g4 * 4 + r;                            \
            int i = rowA + il; (void)i;                                        \
            int li = ((const int*)&lrow[m])[r];                                \
            float ps = 0.f, ns = 0.f;                                          \
            _Pragma("unroll")                                                  \
            for (int n = 0; n < 4; ++n) {                                      \
                int j = rowB + wc * 64 + n * 16 + q15; (void)j;                \
                float sim = acc[m][n][r];                                      \
                float s = score_of(sim);                                       \
                float e = __expf(s);                                           \
                if (VALIDEXPR) {                                               \
                    if (li == ljv[n]) { ps += s; cs[n] += s; }                 \
                    else              { ns += e; cn[n] += e; }                 \
                }                                                              \
            }                                                                  \
            _Pragma("unroll")                                                  \
            for (int off = 1; off < 16; off <<= 1) {                           \
                ps += __shfl_xor(ps, off);                                     \
                ns += __shfl_xor(ns, off);                                     \
            }                                                                  \
            if (q15 == 0) { rowP[wc * 128 + il] = ps; rowN[wc * 128 + il] = ns; } \
        }                                                                      \
    }

    if (fastpath) { EPI(true); }
    else          { EPI(i < NTOT && j < NTOT && i != j); }
#undef EPI

    // col-side: reduce over g4 groups (same q15-column, different rows)
    #pragma unroll
    for (int n = 0; n < 4; ++n) {
        float a = cs[n], bb = cn[n];
        a += __shfl_xor(a, 16); a += __shfl_xor(a, 32);
        bb += __shfl_xor(bb, 16); bb += __shfl_xor(bb, 32);
        if (g4 == 0) {
            colP[wr * 128 + wc * 64 + n * 16 + q15] = a;
            colN[wr * 128 + wc * 64 + n * 16 + q15] = bb;
        }
    }

    __syncthreads();
    if (tid < 128) {
        pP[(size_t)jt * NPAD + rowA + tid] = rowP[tid] + rowP[128 + tid];
        pN[(size_t)jt * NPAD + rowA + tid] = rowN[tid] + rowN[128 + tid];
    } else if (tid < 256 && it != jt) {
        int tt = tid - 128;
        pP[(size_t)it * NPAD + rowB + tt] = colP[tt] + colP[128 + tt] + colP[256 + tt] + colP[384 + tt];
        pN[(size_t)it * NPAD + rowB + tt] = colN[tt] + colN[128 + tt] + colN[256 + tt] + colN[384 + tt];
    }
}

// ---------------- kernel 5: reduce partials -> loss, ticket finalize ----------------
__global__ void kreduce(const float* __restrict__ pP, const float* __restrict__ pN,
                        const int* __restrict__ hist, const int* __restrict__ labs,
                        float* __restrict__ lossacc, unsigned* __restrict__ ticket,
                        float* __restrict__ out) {
    int i = blockIdx.x * 256 + threadIdx.x;
    float lsum = 0.f, lcnt = 0.f;
    if (i < NTOT) {
        float sp = 0.f, sn = 0.f;
        #pragma unroll 5
        for (int c = 0; c < NT; ++c) {
            sp += pP[(size_t)c * NPAD + i];
            sn += pN[(size_t)c * NPAD + i];
        }
        // M = 0 shift: differs from reference's global-max shift by <=~1e-7
        float cnt = (float)hist[labs[i]];
        float pos = sp / (cnt + 1e-8f);
        float neg = logf(sn + 1e-8f);
        float loss = neg - pos;
        if (loss > 0.f) { lsum = loss; lcnt = 1.f; }
    }
    #pragma unroll
    for (int off = 1; off < 64; off <<= 1) {
        lsum += __shfl_xor(lsum, off);
        lcnt += __shfl_xor(lcnt, off);
    }
    __shared__ float s1[4], s2[4];
    int lane = threadIdx.x & 63, w = threadIdx.x >> 6;
    if (lane == 0) { s1[w] = lsum; s2[w] = lcnt; }
    __syncthreads();
    if (threadIdx.x == 0) {
        atomicAdd(&lossacc[0], s1[0] + s1[1] + s1[2] + s1[3]);
        atomicAdd(&lossacc[1], s2[0] + s2[1] + s2[2] + s2[3]);
        __threadfence();
        unsigned tk = atomicAdd(ticket, 1u);
        if (tk == 32) {   // last of 33 blocks: all adds visible
            float a = atomicAdd(&lossacc[0], 0.f);
            float c2 = atomicAdd(&lossacc[1], 0.f);
            out[0] = (c2 > 0.f) ? a / fmaxf(c2, 1.f) : 0.f;
        }
    }
}

// ---------------- launcher ----------------
extern "C" void kernel_launch(void* const* d_in, const int* in_sizes, int n_in,
                              void* d_out, int out_size, void* d_ws, size_t ws_size,
                              hipStream_t stream) {
    const float* feats  = (const float*)d_in[0];
    const int*   labels = (const int*)d_in[1];
    const float* protos = (const float*)d_in[2];
    const float* moms   = (const float*)d_in[3];
    float* out = (float*)d_out;

    char* ws = (char*)d_ws;
    float*    S_      = (float*)(ws + 0);        // 1792 f32 -> 7168
    int*      hist    = (int*)  (ws + 7168);     // 8 int    -> 7200
    float*    lossacc = (float*)(ws + 7200);     // 2 f32    -> 7208
    unsigned* ticket  = (unsigned*)(ws + 7208);  // 1 u32    -> 7212
    float*    wbuf    = (float*)(ws + 7296);     // 8192 f32 -> 40064
    int*      labs    = (int*)  (ws + 40064);    // 8320 int -> 73344
    unsigned char* G  = (unsigned char*)(ws + 73344);    // 8320*256 fp8 -> 2203264
    float*    pP      = (float*)(ws + 2203264);  // 65*8320 f32 -> 4366464
    float*    pN      = (float*)(ws + 4366464);  // 65*8320 f32 -> 6529664

    kprep<<<1, 256, 0, stream>>>(labels, wbuf, labs, hist, S_, lossacc, ticket);
    kaccnorm<<<256, 256, 0, stream>>>(feats, labels, wbuf, S_, (unsigned*)G);
    kproto<<<1, 256, 0, stream>>>(S_, hist, protos, moms, G);
    kmain<<<NBLK, 512, 0, stream>>>(G, labs, pP, pN);
    kreduce<<<33, 256, 0, stream>>>(pP, pN, hist, labs, lossacc, ticket, out);
}